// Round 2
// baseline (217.864 us; speedup 1.0000x reference)
//
#include <hip/hip_runtime.h>

#define BATCH 1024
#define V 20
#define S 30
#define D 128
#define H0 256
#define H1 128
#define NCLASS 20
#define VS (V * S)   // 600

// 512 threads/block, 1024 blocks -> 524288 threads = exactly full occupancy
// (2048 thr/CU, 8 waves/SIMD). Gather is cache-latency-bound; occupancy is
// the throughput knob.
__global__ __launch_bounds__(512, 8) void fcnc_fused_kernel(
    const int* __restrict__ diag_idx,
    const int* __restrict__ proc_idx,
    const float* __restrict__ emb,
    const float* __restrict__ W0, const float* __restrict__ b0,
    const float* __restrict__ W1, const float* __restrict__ b1,
    const float* __restrict__ W2, const float* __restrict__ b2,
    float* __restrict__ out)
{
    __shared__ int sidx[2 * VS];                               // 4.8 KB
    __shared__ __attribute__((aligned(16))) float red[16][D];  // 8 KB
    __shared__ __attribute__((aligned(16))) float x[2 * D];    // 1 KB
    __shared__ __attribute__((aligned(16))) float h0[H0];      // 1 KB
    __shared__ __attribute__((aligned(16))) float h1[H1];      // 0.5 KB

    const int b = blockIdx.x;
    const int tid = threadIdx.x;

    // ---- Phase A: stage indices (vectorized int4: 600 ints = 150 int4 per pool) ----
    {
        const int4* dsrc = (const int4*)(diag_idx + b * VS);
        const int4* psrc = (const int4*)(proc_idx + b * VS);
        if (tid < 150)                        ((int4*)sidx)[tid]            = dsrc[tid];
        else if (tid >= 256 && tid < 406)     ((int4*)(sidx + VS))[tid-256] = psrc[tid-256];
    }
    __syncthreads();

    // ---- Phase B: gather-accumulate ----
    // 16 groups of 32 lanes. Groups 0-7: diag (75 contiguous rows each);
    // groups 8-15: proc. Lane l holds float4 cols [4l,4l+3] -> one row is a
    // fully-coalesced 512B (a wave64 load covers 2 rows = 1KB).
    const int grp  = tid >> 5;
    const int lane = tid & 31;
    const int pool = grp >> 3;
    const int sub  = grp & 7;
    const int* idxp = sidx + pool * VS + sub * 75;
    float4 acc = make_float4(0.f, 0.f, 0.f, 0.f);
    #pragma unroll 5
    for (int r = 0; r < 75; ++r) {
        const int row = idxp[r];                       // uniform per group (LDS broadcast)
        const float4 e = ((const float4*)(emb + row * D))[lane];  // row*D < 2^31, int math
        acc.x += e.x; acc.y += e.y; acc.z += e.z; acc.w += e.w;
    }
    ((float4*)red[grp])[lane] = acc;
    __syncthreads();

    // ---- Phase C: reduce 8 partials/pool -> x[256] = concat(diag,proc)/30 ----
    if (tid < 256) {
        const int p = tid >> 7;          // 0: diag, 1: proc
        const int d = tid & 127;
        float s = 0.f;
        #pragma unroll
        for (int g = 0; g < 8; ++g) s += red[p * 8 + g][d];
        x[tid] = s * (1.0f / 30.0f);     // mean over S then sum over V
    }
    __syncthreads();

    // ---- fc0 (256 -> 256): 2 threads per output row ----
    {
        const int row = tid >> 1, half = tid & 1;
        const float4* w  = (const float4*)(W0 + row * (2 * D) + half * 128);
        const float4* xv = (const float4*)(x + half * 128);
        float a = 0.f;
        #pragma unroll
        for (int k = 0; k < 32; ++k) {
            const float4 wv = w[k], xx = xv[k];
            a += wv.x * xx.x + wv.y * xx.y + wv.z * xx.z + wv.w * xx.w;
        }
        a += __shfl_xor(a, 1);
        if (!half) h0[row] = fmaxf(a + b0[row], 0.f);   // relu before fc1
    }
    __syncthreads();

    // ---- fc1 (256 -> 128): 4 threads per output row ----
    {
        const int row = tid >> 2, q = tid & 3;
        const float4* w  = (const float4*)(W1 + row * H0 + q * 64);
        const float4* hv = (const float4*)(h0 + q * 64);
        float a = 0.f;
        #pragma unroll
        for (int k = 0; k < 16; ++k) {
            const float4 wv = w[k], hh = hv[k];
            a += wv.x * hh.x + wv.y * hh.y + wv.z * hh.z + wv.w * hh.w;
        }
        a += __shfl_xor(a, 1);
        a += __shfl_xor(a, 2);
        if (!q) h1[row] = fmaxf(a + b1[row], 0.f);      // relu before fc2
    }
    __syncthreads();

    // ---- fc2 (128 -> 20): 4 threads per output row, no relu ----
    if (tid < 4 * NCLASS) {
        const int row = tid >> 2, q = tid & 3;
        const float4* w  = (const float4*)(W2 + row * H1 + q * 32);
        const float4* hv = (const float4*)(h1 + q * 32);
        float a = 0.f;
        #pragma unroll
        for (int k = 0; k < 8; ++k) {
            const float4 wv = w[k], hh = hv[k];
            a += wv.x * hh.x + wv.y * hh.y + wv.z * hh.z + wv.w * hh.w;
        }
        a += __shfl_xor(a, 1);
        a += __shfl_xor(a, 2);
        if (!q) out[b * NCLASS + row] = a + b2[row];
    }
}

extern "C" void kernel_launch(void* const* d_in, const int* in_sizes, int n_in,
                              void* d_out, int out_size, void* d_ws, size_t ws_size,
                              hipStream_t stream) {
    const int*   diag_idx = (const int*)d_in[0];
    const int*   proc_idx = (const int*)d_in[1];
    const float* emb      = (const float*)d_in[2];
    const float* W0       = (const float*)d_in[3];
    const float* b0       = (const float*)d_in[4];
    const float* W1       = (const float*)d_in[5];
    const float* b1       = (const float*)d_in[6];
    const float* W2       = (const float*)d_in[7];
    const float* b2       = (const float*)d_in[8];
    float* out = (float*)d_out;

    fcnc_fused_kernel<<<BATCH, 512, 0, stream>>>(
        diag_idx, proc_idx, emb, W0, b0, W1, b1, W2, b2, out);
}

// Round 3
// 184.575 us; speedup vs baseline: 1.1804x; 1.1804x over previous
//
#include <hip/hip_runtime.h>

#define BATCH 1024
#define VS 600          // V*S = 20*30
#define D 128
#define H0 256
#define H1 128
#define NCLASS 20

// ---------------- K1: per-(sample, owner) partial gather-pool ----------------
// Grid 8192 = (sample s = bid>>3, owner x = bid&7). Round-robin dispatch puts
// bid%8 on XCD bid%8 (perf heuristic only; correctness is mapping-independent).
// Block compacts the sample's indices with row&7==x, gathers those rows
// (32 lanes = one coalesced 512B row), and writes a 256-float partial.
__global__ __launch_bounds__(256) void gather_partial_kernel(
    const int* __restrict__ diag_idx, const int* __restrict__ proc_idx,
    const float* __restrict__ emb, float* __restrict__ part)
{
    __shared__ int sidx[2 * VS];                              // 4.8 KB
    __shared__ int list[2 * VS];                              // 4.8 KB (worst case)
    __shared__ int nd, np;
    __shared__ __attribute__((aligned(16))) float red[8][D];  // 4 KB

    const int bid = blockIdx.x;
    const int x   = bid & 7;
    const int s   = bid >> 3;
    const int tid = threadIdx.x;

    // stage indices (300 int4 over 256 threads)
    {
        const int4* dsrc = (const int4*)(diag_idx + s * VS);
        const int4* psrc = (const int4*)(proc_idx + s * VS);
        for (int i = tid; i < 300; i += 256) {
            if (i < 150) ((int4*)sidx)[i]            = dsrc[i];
            else         ((int4*)(sidx + VS))[i-150] = psrc[i-150];
        }
    }
    if (tid == 0) { nd = 0; np = 0; }
    __syncthreads();

    // compact rows owned by x (order irrelevant: sum is commutative)
    for (int i = tid; i < VS; i += 256) {
        const int r = sidx[i];
        if ((r & 7) == x) list[atomicAdd(&nd, 1)] = r;
    }
    for (int i = tid; i < VS; i += 256) {
        const int r = sidx[VS + i];
        if ((r & 7) == x) list[VS + atomicAdd(&np, 1)] = r;
    }
    __syncthreads();

    // gather: 8 groups of 32 lanes; groups 0-3 diag list, 4-7 proc list.
    const int grp = tid >> 5, lane = tid & 31;
    const int pool = grp >> 2, sub = grp & 3;
    const int cnt = pool ? np : nd;           // ~75 per pool, ~19 per group
    const int* lst = list + pool * VS;
    float4 acc = make_float4(0.f, 0.f, 0.f, 0.f);
    #pragma unroll 6
    for (int i = sub; i < cnt; i += 4) {
        const int row = lst[i];               // uniform per group (LDS broadcast)
        const float4 e = ((const float4*)(emb + row * D))[lane];
        acc.x += e.x; acc.y += e.y; acc.z += e.z; acc.w += e.w;
    }
    ((float4*)red[grp])[lane] = acc;
    __syncthreads();

    // reduce 4 groups per pool -> 256-float partial, pre-scaled by 1/30
    {
        const int p = tid >> 7, d = tid & 127;
        const float v = red[p*4+0][d] + red[p*4+1][d] + red[p*4+2][d] + red[p*4+3][d];
        part[(x * BATCH + s) * (2 * D) + tid] = v * (1.0f / 30.0f);
    }
}

// ---------------- K2: reduce 8 partials + fused MLP ----------------
__global__ __launch_bounds__(256) void mlp_kernel(
    const float* __restrict__ part,
    const float* __restrict__ W0, const float* __restrict__ b0,
    const float* __restrict__ W1, const float* __restrict__ b1,
    const float* __restrict__ W2, const float* __restrict__ b2,
    float* __restrict__ out)
{
    __shared__ __attribute__((aligned(16))) float x[2 * D];
    __shared__ __attribute__((aligned(16))) float h0[H0];
    __shared__ __attribute__((aligned(16))) float h1[H1];

    const int s = blockIdx.x, tid = threadIdx.x;

    float v = 0.f;
    #pragma unroll
    for (int xp = 0; xp < 8; ++xp) v += part[(xp * BATCH + s) * (2 * D) + tid];
    x[tid] = v;
    __syncthreads();

    // fc0 (256 -> 256)
    {
        const float4* wrow = (const float4*)(W0 + tid * (2 * D));
        const float4* xv   = (const float4*)x;
        float a = 0.f;
        #pragma unroll 8
        for (int k = 0; k < 64; ++k) {
            const float4 w = wrow[k], xx = xv[k];
            a += w.x * xx.x + w.y * xx.y + w.z * xx.z + w.w * xx.w;
        }
        h0[tid] = fmaxf(a + b0[tid], 0.f);     // relu before fc1
    }
    __syncthreads();

    // fc1 (256 -> 128)
    if (tid < H1) {
        const float4* wrow = (const float4*)(W1 + tid * H0);
        const float4* hv   = (const float4*)h0;
        float a = 0.f;
        #pragma unroll 8
        for (int k = 0; k < 64; ++k) {
            const float4 w = wrow[k], hh = hv[k];
            a += w.x * hh.x + w.y * hh.y + w.z * hh.z + w.w * hh.w;
        }
        h1[tid] = fmaxf(a + b1[tid], 0.f);     // relu before fc2
    }
    __syncthreads();

    // fc2 (128 -> 20), no relu
    if (tid < NCLASS) {
        const float4* wrow = (const float4*)(W2 + tid * H1);
        const float4* hv   = (const float4*)h1;
        float a = 0.f;
        #pragma unroll
        for (int k = 0; k < 32; ++k) {
            const float4 w = wrow[k], hh = hv[k];
            a += w.x * hh.x + w.y * hh.y + w.z * hh.z + w.w * hh.w;
        }
        out[s * NCLASS + tid] = a + b2[tid];
    }
}

extern "C" void kernel_launch(void* const* d_in, const int* in_sizes, int n_in,
                              void* d_out, int out_size, void* d_ws, size_t ws_size,
                              hipStream_t stream) {
    const int*   diag_idx = (const int*)d_in[0];
    const int*   proc_idx = (const int*)d_in[1];
    const float* emb      = (const float*)d_in[2];
    const float* W0       = (const float*)d_in[3];
    const float* b0       = (const float*)d_in[4];
    const float* W1       = (const float*)d_in[5];
    const float* b1       = (const float*)d_in[6];
    const float* W2       = (const float*)d_in[7];
    const float* b2       = (const float*)d_in[8];
    float* out  = (float*)d_out;
    float* part = (float*)d_ws;   // 8 * 1024 * 256 floats = 8 MB

    gather_partial_kernel<<<8 * BATCH, 256, 0, stream>>>(diag_idx, proc_idx, emb, part);
    mlp_kernel<<<BATCH, 256, 0, stream>>>(part, W0, b0, W1, b1, W2, b2, out);
}